// Round 8
// baseline (366.677 us; speedup 1.0000x reference)
//
#include <hip/hip_runtime.h>
#include <cstdint>
#include <cstring>

typedef unsigned short u16;
typedef short bf16x8 __attribute__((ext_vector_type(8)));
typedef float f32x4 __attribute__((ext_vector_type(4)));

#define MFMA16(a,b,c) __builtin_amdgcn_mfma_f32_16x16x32_bf16(a,b,c,0,0,0)

// ---------- helpers ----------

__device__ __forceinline__ u16 f2bf(float f) {
  union { float f; uint32_t u; } un; un.f = f;
  uint32_t u = un.u;
  u += 0x7FFFu + ((u >> 16) & 1u);   // RNE
  return (u16)(u >> 16);
}

__device__ __forceinline__ float bf2f(u16 h) {
  union { uint32_t u; float f; } un; un.u = ((uint32_t)h) << 16;
  return un.f;
}

// tanh-form GELU via HW v_exp_f32 (~12 VALU ops vs ~100 for OCML erff).
__device__ __forceinline__ float gelu_fast(float v) {
  float u = 0.7978845608028654f * (v + 0.044715f * v * v * v);
  float e = __expf(2.f * u);                 // tanh(u) = 1 - 2/(e+1)
  float th = 1.f - __fdividef(2.f, e + 1.f);
  return 0.5f * v * (1.f + th);
}

__device__ __forceinline__ void gl_lds16(const void* g, void* l) {
  __builtin_amdgcn_global_load_lds(
      (__attribute__((address_space(1))) void*)(const_cast<void*>(g)),
      (__attribute__((address_space(3))) void*)l, 16, 0, 0);
}

// ---------- fused weight transpose + f32->bf16 : W[K][N] -> Wt[N][K] ----------
// 64x64 tiles, float4 loads (16B/lane), ushort4 stores.  3072 blocks.

__global__ __launch_bounds__(256) void transpose_all(
    const float* __restrict__ wa, const float* __restrict__ wp,
    const float* __restrict__ wf, const float* __restrict__ wf2,
    u16* __restrict__ wat, u16* __restrict__ wpt,
    u16* __restrict__ wft, u16* __restrict__ wf2t)
{
  __shared__ float tile[64][65];
  int id = blockIdx.x;
  const float* W; u16* Wt; int K, N, bx, by;
  if (id < 768)       { W = wa;  Wt = wat;  K = 1024; N = 3072; bx = id % 48; by = id / 48; }
  else if (id < 1024) { id -= 768;  W = wp;  Wt = wpt;  K = 1024; N = 1024; bx = id % 16; by = id / 16; }
  else if (id < 2048) { id -= 1024; W = wf;  Wt = wft;  K = 1024; N = 4096; bx = id % 64; by = id / 64; }
  else                { id -= 2048; W = wf2; Wt = wf2t; K = 4096; N = 1024; bx = id % 16; by = id / 16; }
  int kt = by * 64, nt = bx * 64;
  int tid = threadIdx.x;
  int tx = tid & 15, ty = tid >> 4;                // 16 x 16
#pragma unroll
  for (int i = 0; i < 4; ++i) {
    int r = ty + i * 16;
    float4 v = *(const float4*)&W[(size_t)(kt + r) * N + nt + tx * 4];
    tile[r][tx * 4 + 0] = v.x;
    tile[r][tx * 4 + 1] = v.y;
    tile[r][tx * 4 + 2] = v.z;
    tile[r][tx * 4 + 3] = v.w;
  }
  __syncthreads();
#pragma unroll
  for (int i = 0; i < 4; ++i) {
    int n = ty + i * 16;
    ushort4 o4;
    o4.x = f2bf(tile[tx * 4 + 0][n]);
    o4.y = f2bf(tile[tx * 4 + 1][n]);
    o4.z = f2bf(tile[tx * 4 + 2][n]);
    o4.w = f2bf(tile[tx * 4 + 3][n]);
    *(ushort4*)&Wt[(size_t)(nt + n) * K + kt + tx * 4] = o4;
  }
}

// ---------- LayerNorm (f32 in -> bf16 out), one block per row of 1024 ----------

__global__ __launch_bounds__(256) void ln_bf16(
    const float* __restrict__ x, const float* __restrict__ wt,
    const float* __restrict__ bs, u16* __restrict__ out)
{
  int row = blockIdx.x;
  int tid = threadIdx.x, lane = tid & 63, w = tid >> 6;
  const float* xr = x + (size_t)row * 1024;
  float4 v = *(const float4*)(xr + tid * 4);
  float s = v.x + v.y + v.z + v.w;
  float sq = v.x * v.x + v.y * v.y + v.z * v.z + v.w * v.w;
#pragma unroll
  for (int o = 1; o < 64; o <<= 1) { s += __shfl_xor(s, o); sq += __shfl_xor(sq, o); }
  __shared__ float ls[4], lq[4];
  if (lane == 0) { ls[w] = s; lq[w] = sq; }
  __syncthreads();
  s = ls[0] + ls[1] + ls[2] + ls[3];
  sq = lq[0] + lq[1] + lq[2] + lq[3];
  float mu = s * (1.f / 1024.f);
  float var = sq * (1.f / 1024.f) - mu * mu;
  float rstd = rsqrtf(var + 1e-5f);
  float4 wv = *(const float4*)(wt + tid * 4);
  float4 bv = *(const float4*)(bs + tid * 4);
  ushort4 o4;
  o4.x = f2bf((v.x - mu) * rstd * wv.x + bv.x);
  o4.y = f2bf((v.y - mu) * rstd * wv.y + bv.y);
  o4.z = f2bf((v.z - mu) * rstd * wv.z + bv.z);
  o4.w = f2bf((v.w - mu) * rstd * wv.w + bv.w);
  *(ushort4*)(out + (size_t)row * 1024 + tid * 4) = o4;
}

// ---------- GEMM mainloop, double-buffered LDS, one barrier per K-iter ----------
// LDS bank-conflict fix (verified: 0 conflicts): chunk-XOR swizzle realized as
// pre-swizzled GLOBAL source (linear gl_lds dest) + XOR'd ds_read offset.

__device__ __forceinline__ void gemm_mainloop_db(
    const u16* __restrict__ Abase, const u16* __restrict__ Bbase,
    int lda, int ldb, int nIter, f32x4 acc[4][4])
{
  __shared__ __align__(16) u16 lA[2][128 * 32];
  __shared__ __align__(16) u16 lB[2][128 * 32];

  const int tid = threadIdx.x;
  const int lane = tid & 63;
  const int w = tid >> 6;
  const int wr = (w >> 1) * 64;
  const int wc = (w & 1) * 64;
  const int laneM = lane & 15;
  const int q4 = lane >> 4;

#pragma unroll
  for (int i = 0; i < 4; ++i)
#pragma unroll
    for (int j = 0; j < 4; ++j)
      acc[i][j] = f32x4{0.f, 0.f, 0.f, 0.f};

  const int off0 = w * 1024 + lane * 16;           // linear LDS dest (bytes)
  const int off1 = off0 + 4096;
  const int rA0 = off0 >> 6;
  const int rA1 = off1 >> 6;
  const int scb = (((lane & 3) ^ ((lane >> 3) & 3)) << 4);  // swizzled src chunk

  const size_t sA = (size_t)lda * 2;
  const size_t sB = (size_t)ldb * 2;
  const char* pA0 = (const char*)Abase + (size_t)rA0 * sA + scb;
  const char* pA1 = (const char*)Abase + (size_t)rA1 * sA + scb;
  const char* pB0 = (const char*)Bbase + (size_t)rA0 * sB + scb;
  const char* pB1 = (const char*)Bbase + (size_t)rA1 * sB + scb;
  char* dA0 = (char*)&lA[0][0] + off0;
  char* dA1 = (char*)&lA[0][0] + off1;
  char* dB0 = (char*)&lB[0][0] + off0;
  char* dB1 = (char*)&lB[0][0] + off1;

  gl_lds16(pA0, dA0); gl_lds16(pA1, dA1);
  gl_lds16(pB0, dB0); gl_lds16(pB1, dB1);
  pA0 += 64; pA1 += 64; pB0 += 64; pB1 += 64;
  __syncthreads();

  const int rdswz = ((q4 ^ ((laneM >> 1) & 3)) << 4);

  for (int it = 0; it < nIter; ++it) {
    const int cur = it & 1;
    const int nb = cur ^ 1;
    if (it + 1 < nIter) {
      gl_lds16(pA0, dA0 + nb * 8192);
      gl_lds16(pA1, dA1 + nb * 8192);
      gl_lds16(pB0, dB0 + nb * 8192);
      gl_lds16(pB1, dB1 + nb * 8192);
      pA0 += 64; pA1 += 64; pB0 += 64; pB1 += 64;
    }
    const char* aRd = (const char*)&lA[cur][0] + (wr + laneM) * 64 + rdswz;
    const char* bRd = (const char*)&lB[cur][0] + (wc + laneM) * 64 + rdswz;
    bf16x8 af[4], bfr[4];
#pragma unroll
    for (int t = 0; t < 4; ++t) {
      af[t]  = *(const bf16x8*)(aRd + t * 1024);
      bfr[t] = *(const bf16x8*)(bRd + t * 1024);
    }
#pragma unroll
    for (int i = 0; i < 4; ++i)
#pragma unroll
      for (int j = 0; j < 4; ++j)
        acc[i][j] = MFMA16(af[i], bfr[j], acc[i][j]);
    if (it + 1 < nIter) __syncthreads();
  }
}

// ---------- GEMM kernels with fused epilogues ----------
// __launch_bounds__(256,4): 4 blocks/CU resident (LDS 32KB*4=128<=160KB).

// qkv: C = h @ w_attnT^T + b_attn; q,k -> [bh][t][d]; v -> [bh][d][t] (V^T)
__global__ __launch_bounds__(256, 4) void gemm_qkv(
    const u16* __restrict__ A, const u16* __restrict__ Bt,
    const float* __restrict__ bias,
    u16* __restrict__ qo, u16* __restrict__ ko, u16* __restrict__ vo)
{
  f32x4 acc[4][4];
  int m0 = blockIdx.y * 128, n0 = blockIdx.x * 128;
  gemm_mainloop_db(A + (size_t)m0 * 1024, Bt + (size_t)n0 * 1024, 1024, 1024, 32, acc);
  const int lane = threadIdx.x & 63, w = threadIdx.x >> 6;
  const int wr = (w >> 1) * 64, wc = (w & 1) * 64;
  const int laneM = lane & 15, q4 = lane >> 4;
  const int which = (n0 >> 10);
#pragma unroll
  for (int ti = 0; ti < 4; ++ti) {
#pragma unroll
    for (int tj = 0; tj < 4; ++tj) {
      int n = n0 + wc + tj * 16 + laneM;
      int c = n & 1023;
      int hh = c >> 6, d = c & 63;
      float bval = bias[n];
      if (which == 2) {
        int m0r = m0 + wr + ti * 16 + q4 * 4;
        int b = m0r >> 10, t0 = m0r & 1023;
        ushort4 o4;
        o4.x = f2bf(acc[ti][tj][0] + bval);
        o4.y = f2bf(acc[ti][tj][1] + bval);
        o4.z = f2bf(acc[ti][tj][2] + bval);
        o4.w = f2bf(acc[ti][tj][3] + bval);
        *(ushort4*)&vo[((size_t)((b * 16 + hh) * 64 + d)) * 1024 + t0] = o4;
      } else {
        u16* dst = (which == 0) ? qo : ko;
#pragma unroll
        for (int r = 0; r < 4; ++r) {
          int m = m0 + wr + ti * 16 + q4 * 4 + r;
          int b = m >> 10, t = m & 1023;
          dst[((size_t)((b * 16 + hh) * 1024 + t)) * 64 + d] = f2bf(acc[ti][tj][r] + bval);
        }
      }
    }
  }
}

// proj: x2 = (x + y @ w_projT^T + b_proj) * mask[row]
__global__ __launch_bounds__(256, 4) void gemm_proj(
    const u16* __restrict__ A, const u16* __restrict__ Bt,
    const float* __restrict__ bias, const float* __restrict__ xin,
    const float* __restrict__ maskv, float* __restrict__ x2)
{
  f32x4 acc[4][4];
  int m0 = blockIdx.y * 128, n0 = blockIdx.x * 128;
  gemm_mainloop_db(A + (size_t)m0 * 1024, Bt + (size_t)n0 * 1024, 1024, 1024, 32, acc);
  const int lane = threadIdx.x & 63, w = threadIdx.x >> 6;
  const int wr = (w >> 1) * 64, wc = (w & 1) * 64;
  const int laneM = lane & 15, q4 = lane >> 4;
#pragma unroll
  for (int ti = 0; ti < 4; ++ti) {
#pragma unroll
    for (int tj = 0; tj < 4; ++tj) {
      int n = n0 + wc + tj * 16 + laneM;
      float bval = bias[n];
#pragma unroll
      for (int r = 0; r < 4; ++r) {
        int m = m0 + wr + ti * 16 + q4 * 4 + r;
        float v = xin[(size_t)m * 1024 + n] + acc[ti][tj][r] + bval;
        x2[(size_t)m * 1024 + n] = v * maskv[m];
      }
    }
  }
}

// fc: f = gelu(h2 @ w_fcT^T + b_fc) -> bf16   (fast tanh-form GELU)
__global__ __launch_bounds__(256, 4) void gemm_fc(
    const u16* __restrict__ A, const u16* __restrict__ Bt,
    const float* __restrict__ bias, u16* __restrict__ fo)
{
  f32x4 acc[4][4];
  int m0 = blockIdx.y * 128, n0 = blockIdx.x * 128;
  gemm_mainloop_db(A + (size_t)m0 * 1024, Bt + (size_t)n0 * 1024, 1024, 1024, 32, acc);
  const int lane = threadIdx.x & 63, w = threadIdx.x >> 6;
  const int wr = (w >> 1) * 64, wc = (w & 1) * 64;
  const int laneM = lane & 15, q4 = lane >> 4;
#pragma unroll
  for (int ti = 0; ti < 4; ++ti) {
#pragma unroll
    for (int tj = 0; tj < 4; ++tj) {
      int n = n0 + wc + tj * 16 + laneM;
      float bval = bias[n];
#pragma unroll
      for (int r = 0; r < 4; ++r) {
        int m = m0 + wr + ti * 16 + q4 * 4 + r;
        fo[(size_t)m * 4096 + n] = f2bf(gelu_fast(acc[ti][tj][r] + bval));
      }
    }
  }
}

// fc2 split-K=4, XCD-swizzled, bf16 partials.
__global__ __launch_bounds__(256, 4) void gemm_fc2_splitk(
    const u16* __restrict__ A, const u16* __restrict__ Bt,
    u16* __restrict__ pall)
{
  int id = blockIdx.x;            // 0..1023
  int r = id & 7, j = id >> 3;    // r = XCD slot, j = 0..127
  int mt = r * 4 + (j >> 5);      // m-tile 0..31 (4 per XCD)
  int rem = j & 31;
  int n0 = (rem & 7) * 128;       // n fastest: same-XCD neighbors share A slice
  int kz = rem >> 3;              // k-quarter 0..3
  int m0 = mt * 128;
  f32x4 acc[4][4];
  gemm_mainloop_db(A + (size_t)m0 * 4096 + kz * 1024,
                   Bt + (size_t)n0 * 4096 + kz * 1024, 4096, 4096, 32, acc);
  u16* p = pall + (size_t)kz * 4096 * 1024;
  const int lane = threadIdx.x & 63, w = threadIdx.x >> 6;
  const int wr = (w >> 1) * 64, wc = (w & 1) * 64;
  const int laneM = lane & 15, q4 = lane >> 4;
#pragma unroll
  for (int ti = 0; ti < 4; ++ti) {
#pragma unroll
    for (int tj = 0; tj < 4; ++tj) {
      int n = n0 + wc + tj * 16 + laneM;
#pragma unroll
      for (int r2 = 0; r2 < 4; ++r2) {
        int m = m0 + wr + ti * 16 + q4 * 4 + r2;
        p[(size_t)m * 1024 + n] = f2bf(acc[ti][tj][r2]);
      }
    }
  }
}

// out = x2 + b_fc2 + sum_z p[z]   (p bf16)
__global__ __launch_bounds__(256) void fc2_finalize(
    const float* __restrict__ x2, const float* __restrict__ bias,
    const u16* __restrict__ pall, float* __restrict__ out)
{
  int i = blockIdx.x * 256 + threadIdx.x;      // float4 index
  int col4 = i & 255;
  float4 a = ((const float4*)x2)[i];
  float4 b = ((const float4*)bias)[col4];
  float s0 = a.x + b.x, s1 = a.y + b.y, s2 = a.z + b.z, s3 = a.w + b.w;
#pragma unroll
  for (int z = 0; z < 4; ++z) {
    ushort4 u = ((const ushort4*)(pall + (size_t)z * 4194304))[i];
    s0 += bf2f(u.x); s1 += bf2f(u.y); s2 += bf2f(u.z); s3 += bf2f(u.w);
  }
  float4 o; o.x = s0; o.y = s1; o.z = s2; o.w = s3;
  ((float4*)out)[i] = o;
}

// ---------- attention: 8 waves/block, q-tile=128 (16 rows/wave), two-pass,
// double-buffered K/V with register-staged prefetch (one barrier per k-tile),
// LDS importance accumulator, s_setprio around MFMA clusters.  V^T layout.
// r8: (a) grid remap so id%8 = bh%8 -> all 8 q-tiles of a head share one XCD
// (K/V fetched from HBM once per XCD; r7 FETCH was 57.5MB vs ~33 ideal);
// (b) K/V/P tiles are [rows][64] u16 with 16B-chunk XOR swizzle
// (physical chunk = logical chunk ^ (row&7)) on both write and read sides —
// same family as the GEMM swizzle that measured 0 conflicts; replaces the
// +8 pad whose 36-dword stride caused 3.8M conflict cycles (r7 PMC). ----------

__global__ __launch_bounds__(512) void attn_fwd(
    const u16* __restrict__ qb, const u16* __restrict__ kb, const u16* __restrict__ vtb,
    u16* __restrict__ yb, float* __restrict__ part)
{
  const int id = blockIdx.x;
  const int qbi = (id >> 3) & 7;                      // cycles fastest: heavy+light mixed
  const int bh = (id & 7) | (((id >> 6) & 7) << 3);   // id%8 = bh%8 -> same XCD per head
  const int b = bh >> 4, h = bh & 15;

  const int tid = threadIdx.x, lane = tid & 63, w = tid >> 6;   // w in 0..7
  const int q0 = qbi * 128;
  const int laneM = lane & 15, q4 = lane >> 4;
  const int lm7 = laneM & 7;
  const float scale = 0.125f;

  __shared__ __align__(16) u16 lK[2][64 * 64];
  __shared__ __align__(16) u16 lV[2][64 * 64];
  __shared__ __align__(16) u16 lP[8][16 * 64];
  __shared__ float part_s[1024];
  // 16KB + 16KB + 16KB + 4KB = 52KB

  part_s[tid] = 0.f;
  part_s[tid + 512] = 0.f;

  // wave w owns q rows q0 + w*16 .. +15
  bf16x8 qf[2];
  {
    const u16* qrow = qb + ((size_t)(bh * 1024 + q0 + w * 16 + laneM)) * 64 + q4 * 8;
    qf[0] = *(const bf16x8*)qrow;
    qf[1] = *(const bf16x8*)(qrow + 32);
  }

  const int nkt = 2 * qbi + 2;
  const int srow = tid >> 3;                       // 0..63, one uint4/thread/tile
  const int scol = (tid & 7) * 8;                  // global column (u16)
  const int sdst = srow * 64 + (((tid & 7) ^ (srow & 7)) << 3);  // swizzled LDS dst
  const u16* kbase = kb + (size_t)bh * 65536;
  const u16* vbase = vtb + (size_t)bh * 65536;

  // ---- pass 1: denominators (row sums of exp) ----
  float lrow[4] = {0.f, 0.f, 0.f, 0.f};
  {
    uint4 pk = *(const uint4*)(kbase + (size_t)srow * 64 + scol);
    *(uint4*)&lK[0][sdst] = pk;
    __syncthreads();
    for (int kt = 0; kt < nkt; ++kt) {
      const int cur = kt & 1;
      if (kt + 1 < nkt)
        pk = *(const uint4*)(kbase + (size_t)((kt + 1) * 64 + srow) * 64 + scol);
#pragma unroll
      for (int tj = 0; tj < 4; ++tj) {
        const u16* rowp = &lK[cur][(tj * 16 + laneM) * 64];
        const int c0 = (q4 ^ lm7) << 3;
        bf16x8 k0 = *(const bf16x8*)(rowp + c0);
        bf16x8 k1 = *(const bf16x8*)(rowp + (c0 ^ 32));
        f32x4 z = {0.f, 0.f, 0.f, 0.f};
        __builtin_amdgcn_s_setprio(1);
        z = MFMA16(qf[0], k0, z);
        z = MFMA16(qf[1], k1, z);
        __builtin_amdgcn_s_setprio(0);
        int kc = kt * 64 + tj * 16 + laneM;
#pragma unroll
        for (int r = 0; r < 4; ++r) {
          int qg = q0 + w * 16 + q4 * 4 + r;
          lrow[r] += (kc <= qg) ? __expf(z[r] * scale) : 0.f;
        }
      }
      if (kt + 1 < nkt) *(uint4*)&lK[cur ^ 1][sdst] = pk;
      __syncthreads();
    }
  }
  float linv[4];
#pragma unroll
  for (int r = 0; r < 4; ++r) {
    float s = lrow[r];
    s += __shfl_xor(s, 1); s += __shfl_xor(s, 2);
    s += __shfl_xor(s, 4); s += __shfl_xor(s, 8);
    linv[r] = 1.f / s;
  }

  // ---- pass 2: P (normalized), importance column sums, PV ----
  f32x4 o_[4];
#pragma unroll
  for (int dt = 0; dt < 4; ++dt) o_[dt] = f32x4{0.f, 0.f, 0.f, 0.f};

  {
    uint4 pk = *(const uint4*)(kbase + (size_t)srow * 64 + scol);
    uint4 pv = *(const uint4*)(vbase + (size_t)srow * 1024 + scol);
    *(uint4*)&lK[0][sdst] = pk;
    *(uint4*)&lV[0][sdst] = pv;
    __syncthreads();
    for (int kt = 0; kt < nkt; ++kt) {
      const int cur = kt & 1;
      if (kt + 1 < nkt) {
        pk = *(const uint4*)(kbase + (size_t)((kt + 1) * 64 + srow) * 64 + scol);
        pv = *(const uint4*)(vbase + (size_t)srow * 1024 + (kt + 1) * 64 + scol);
      }
      u16* lPw = &lP[w][0];
#pragma unroll
      for (int tj = 0; tj < 4; ++tj) {
        const u16* rowp = &lK[cur][(tj * 16 + laneM) * 64];
        const int c0 = (q4 ^ lm7) << 3;
        bf16x8 k0 = *(const bf16x8*)(rowp + c0);
        bf16x8 k1 = *(const bf16x8*)(rowp + (c0 ^ 32));
        f32x4 z = {0.f, 0.f, 0.f, 0.f};
        __builtin_amdgcn_s_setprio(1);
        z = MFMA16(qf[0], k0, z);
        z = MFMA16(qf[1], k1, z);
        __builtin_amdgcn_s_setprio(0);
        int kc = kt * 64 + tj * 16 + laneM;
        float cs = 0.f;
#pragma unroll
        for (int r = 0; r < 4; ++r) {
          int qg = q0 + w * 16 + q4 * 4 + r;
          float pvf = (kc <= qg) ? __expf(z[r] * scale) * linv[r] : 0.f;
          cs += pvf;
          int prow = q4 * 4 + r;                 // local q row 0..15
          int col = tj * 16 + laneM;             // k col 0..63
          lPw[prow * 64 + ((((col >> 3) ^ (prow & 7)) << 3) | (col & 7))] = f2bf(pvf);
        }
        cs += __shfl_xor(cs, 16);
        cs += __shfl_xor(cs, 32);
        if (lane < 16) atomicAdd(&part_s[kt * 64 + tj * 16 + lane], cs);
      }
      __builtin_amdgcn_s_setprio(1);
#pragma unroll
      for (int ss = 0; ss < 2; ++ss) {
        const int pc = (((ss << 2) | q4) ^ lm7) << 3;
        bf16x8 pf = *(const bf16x8*)&lP[w][laneM * 64 + pc];
#pragma unroll
        for (int dt = 0; dt < 4; ++dt) {
          bf16x8 vf = *(const bf16x8*)&lV[cur][(dt * 16 + laneM) * 64 + pc];
          o_[dt] = MFMA16(pf, vf, o_[dt]);
        }
      }
      __builtin_amdgcn_s_setprio(0);
      if (kt + 1 < nkt) {
        *(uint4*)&lK[cur ^ 1][sdst] = pk;
        *(uint4*)&lV[cur ^ 1][sdst] = pv;
      }
      __syncthreads();
    }
  }

  // flush importance: one global atomicAdd per valid column
  const int kmax = nkt * 64;
  for (int i = tid; i < kmax; i += 512)
    atomicAdd(&part[(size_t)bh * 1024 + i], part_s[i]);

#pragma unroll
  for (int dt = 0; dt < 4; ++dt)
#pragma unroll
    for (int r = 0; r < 4; ++r) {
      int qg = q0 + w * 16 + q4 * 4 + r;
      yb[((size_t)(b * 1024 + qg)) * 1024 + h * 64 + dt * 16 + laneM] = f2bf(o_[dt][r]);
    }
}

// ---------- importance -> mask ----------

__global__ __launch_bounds__(256) void finalize_mask(
    const float* __restrict__ part, const float* __restrict__ amask,
    const float* __restrict__ thr, float* __restrict__ mask_ws,
    float* __restrict__ out_mask, float* __restrict__ out_loss)
{
  int i = blockIdx.x * 256 + threadIdx.x;
  if (i >= 4096) return;
  int b = i >> 10;
  int t = i & 1023;
  float s = 0.f;
#pragma unroll
  for (int hh = 0; hh < 16; ++hh) s += part[(size_t)(b * 16 + hh) * 1024 + t];
  float imp = s * (1.0f / 16384.0f);
  float mv = (imp >= thr[0]) ? amask[i] : 0.f;
  mask_ws[i] = mv;
  out_mask[i] = mv;
  if (i == 0) out_loss[0] = 0.f;
}

// ---------- host ----------

extern "C" void kernel_launch(void* const* d_in, const int* in_sizes, int n_in,
                              void* d_out, int out_size, void* d_ws, size_t ws_size,
                              hipStream_t stream) {
  const float* x      = (const float*)d_in[0];
  const float* amask  = (const float*)d_in[1];
  const float* ln1w   = (const float*)d_in[2];
  const float* ln1b   = (const float*)d_in[3];
  const float* w_attn = (const float*)d_in[4];
  const float* b_attn = (const float*)d_in[5];
  const float* w_proj = (const float*)d_in[6];
  const float* b_proj = (const float*)d_in[7];
  const float* thr    = (const float*)d_in[8];
  const float* ln2w   = (const float*)d_in[9];
  const float* ln2b   = (const float*)d_in[10];
  const float* w_fc   = (const float*)d_in[11];
  const float* b_fc   = (const float*)d_in[12];
  const float* w_fc2  = (const float*)d_in[13];
  const float* b_fc2  = (const float*)d_in[14];
  float* out = (float*)d_out;

  char* ws = (char*)d_ws;
  size_t off = 0;
  auto alloc = [&](size_t bytes) -> char* {
    char* p = ws + off;
    off += (bytes + 255) & ~(size_t)255;
    return p;
  };
  u16* wattnT = (u16*)alloc((size_t)3072 * 1024 * 2);
  u16* wprojT = (u16*)alloc((size_t)1024 * 1024 * 2);
  u16* wfcT   = (u16*)alloc((size_t)4096 * 1024 * 2);
  u16* wfc2T  = (u16*)alloc((size_t)1024 * 4096 * 2);
  u16* hbuf   = (u16*)alloc((size_t)4096 * 1024 * 2);
  // qbuf/kbuf/vtbuf/ybuf: 4 x 8 MB, contiguous; dead before fc2 (aliased as pall)
  u16* qbuf   = (u16*)alloc((size_t)64 * 1024 * 64 * 2);
  u16* kbuf   = (u16*)alloc((size_t)64 * 1024 * 64 * 2);
  u16* vtbuf  = (u16*)alloc((size_t)64 * 64 * 1024 * 2);
  u16* ybuf   = (u16*)alloc((size_t)4096 * 1024 * 2);
  float* part = (float*)alloc((size_t)64 * 1024 * 4);
  float* maskws = (float*)alloc((size_t)4096 * 4);
  float* x2   = (float*)alloc((size_t)4096 * 1024 * 4);
  u16* h2     = (u16*)alloc((size_t)4096 * 1024 * 2);
  u16* fbuf   = (u16*)alloc((size_t)4096 * 4096 * 2);

  u16* pall = qbuf;   // 4 bf16 partials x 8 MB alias q/k/vt/y

  transpose_all<<<3072, 256, 0, stream>>>(
      w_attn, w_proj, w_fc, w_fc2, wattnT, wprojT, wfcT, wfc2T);

  hipMemsetAsync(part, 0, (size_t)64 * 1024 * 4, stream);

  ln_bf16<<<4096, 256, 0, stream>>>(x, ln1w, ln1b, hbuf);

  gemm_qkv<<<dim3(24, 32), 256, 0, stream>>>(hbuf, wattnT, b_attn, qbuf, kbuf, vtbuf);

  attn_fwd<<<512, 512, 0, stream>>>(qbuf, kbuf, vtbuf, ybuf, part);

  finalize_mask<<<16, 256, 0, stream>>>(part, amask, thr, maskws,
                                        out + 4194304, out + 4198400);

  gemm_proj<<<dim3(8, 32), 256, 0, stream>>>(ybuf, wprojT, b_proj, x, maskws, x2);

  ln_bf16<<<4096, 256, 0, stream>>>(x2, ln2w, ln2b, h2);

  gemm_fc<<<dim3(32, 32), 256, 0, stream>>>(h2, wfcT, b_fc, fbuf);

  gemm_fc2_splitk<<<1024, 256, 0, stream>>>(fbuf, wfc2T, pall);

  fc2_finalize<<<4096, 256, 0, stream>>>(x2, b_fc2, pall, out);
}

// Round 9
// 343.889 us; speedup vs baseline: 1.0663x; 1.0663x over previous
//
#include <hip/hip_runtime.h>
#include <cstdint>
#include <cstring>

typedef unsigned short u16;
typedef short bf16x8 __attribute__((ext_vector_type(8)));
typedef float f32x4 __attribute__((ext_vector_type(4)));

#define MFMA16(a,b,c) __builtin_amdgcn_mfma_f32_16x16x32_bf16(a,b,c,0,0,0)

// ---------- helpers ----------

__device__ __forceinline__ u16 f2bf(float f) {
  union { float f; uint32_t u; } un; un.f = f;
  uint32_t u = un.u;
  u += 0x7FFFu + ((u >> 16) & 1u);   // RNE
  return (u16)(u >> 16);
}

__device__ __forceinline__ float bf2f(u16 h) {
  union { uint32_t u; float f; } un; un.u = ((uint32_t)h) << 16;
  return un.f;
}

// tanh-form GELU via HW v_exp_f32 (~12 VALU ops vs ~100 for OCML erff).
__device__ __forceinline__ float gelu_fast(float v) {
  float u = 0.7978845608028654f * (v + 0.044715f * v * v * v);
  float e = __expf(2.f * u);                 // tanh(u) = 1 - 2/(e+1)
  float th = 1.f - __fdividef(2.f, e + 1.f);
  return 0.5f * v * (1.f + th);
}

__device__ __forceinline__ void gl_lds16(const void* g, void* l) {
  __builtin_amdgcn_global_load_lds(
      (__attribute__((address_space(1))) void*)(const_cast<void*>(g)),
      (__attribute__((address_space(3))) void*)l, 16, 0, 0);
}

// ---------- fused weight transpose + f32->bf16 : W[K][N] -> Wt[N][K] ----------
// 64x64 tiles, float4 loads (16B/lane), ushort4 stores.  3072 blocks.

__global__ __launch_bounds__(256) void transpose_all(
    const float* __restrict__ wa, const float* __restrict__ wp,
    const float* __restrict__ wf, const float* __restrict__ wf2,
    u16* __restrict__ wat, u16* __restrict__ wpt,
    u16* __restrict__ wft, u16* __restrict__ wf2t)
{
  __shared__ float tile[64][65];
  int id = blockIdx.x;
  const float* W; u16* Wt; int K, N, bx, by;
  if (id < 768)       { W = wa;  Wt = wat;  K = 1024; N = 3072; bx = id % 48; by = id / 48; }
  else if (id < 1024) { id -= 768;  W = wp;  Wt = wpt;  K = 1024; N = 1024; bx = id % 16; by = id / 16; }
  else if (id < 2048) { id -= 1024; W = wf;  Wt = wft;  K = 1024; N = 4096; bx = id % 64; by = id / 64; }
  else                { id -= 2048; W = wf2; Wt = wf2t; K = 4096; N = 1024; bx = id % 16; by = id / 16; }
  int kt = by * 64, nt = bx * 64;
  int tid = threadIdx.x;
  int tx = tid & 15, ty = tid >> 4;                // 16 x 16
#pragma unroll
  for (int i = 0; i < 4; ++i) {
    int r = ty + i * 16;
    float4 v = *(const float4*)&W[(size_t)(kt + r) * N + nt + tx * 4];
    tile[r][tx * 4 + 0] = v.x;
    tile[r][tx * 4 + 1] = v.y;
    tile[r][tx * 4 + 2] = v.z;
    tile[r][tx * 4 + 3] = v.w;
  }
  __syncthreads();
#pragma unroll
  for (int i = 0; i < 4; ++i) {
    int n = ty + i * 16;
    ushort4 o4;
    o4.x = f2bf(tile[tx * 4 + 0][n]);
    o4.y = f2bf(tile[tx * 4 + 1][n]);
    o4.z = f2bf(tile[tx * 4 + 2][n]);
    o4.w = f2bf(tile[tx * 4 + 3][n]);
    *(ushort4*)&Wt[(size_t)(nt + n) * K + kt + tx * 4] = o4;
  }
}

// ---------- LayerNorm (f32 in -> bf16 out), one block per row of 1024 ----------

__global__ __launch_bounds__(256) void ln_bf16(
    const float* __restrict__ x, const float* __restrict__ wt,
    const float* __restrict__ bs, u16* __restrict__ out)
{
  int row = blockIdx.x;
  int tid = threadIdx.x, lane = tid & 63, w = tid >> 6;
  const float* xr = x + (size_t)row * 1024;
  float4 v = *(const float4*)(xr + tid * 4);
  float s = v.x + v.y + v.z + v.w;
  float sq = v.x * v.x + v.y * v.y + v.z * v.z + v.w * v.w;
#pragma unroll
  for (int o = 1; o < 64; o <<= 1) { s += __shfl_xor(s, o); sq += __shfl_xor(sq, o); }
  __shared__ float ls[4], lq[4];
  if (lane == 0) { ls[w] = s; lq[w] = sq; }
  __syncthreads();
  s = ls[0] + ls[1] + ls[2] + ls[3];
  sq = lq[0] + lq[1] + lq[2] + lq[3];
  float mu = s * (1.f / 1024.f);
  float var = sq * (1.f / 1024.f) - mu * mu;
  float rstd = rsqrtf(var + 1e-5f);
  float4 wv = *(const float4*)(wt + tid * 4);
  float4 bv = *(const float4*)(bs + tid * 4);
  ushort4 o4;
  o4.x = f2bf((v.x - mu) * rstd * wv.x + bv.x);
  o4.y = f2bf((v.y - mu) * rstd * wv.y + bv.y);
  o4.z = f2bf((v.z - mu) * rstd * wv.z + bv.z);
  o4.w = f2bf((v.w - mu) * rstd * wv.w + bv.w);
  *(ushort4*)(out + (size_t)row * 1024 + tid * 4) = o4;
}

// ---------- GEMM mainloop, double-buffered LDS, one barrier per K-iter ----------
// LDS bank-conflict fix (verified: 0 conflicts): chunk-XOR swizzle realized as
// pre-swizzled GLOBAL source (linear gl_lds dest) + XOR'd ds_read offset.

__device__ __forceinline__ void gemm_mainloop_db(
    const u16* __restrict__ Abase, const u16* __restrict__ Bbase,
    int lda, int ldb, int nIter, f32x4 acc[4][4])
{
  __shared__ __align__(16) u16 lA[2][128 * 32];
  __shared__ __align__(16) u16 lB[2][128 * 32];

  const int tid = threadIdx.x;
  const int lane = tid & 63;
  const int w = tid >> 6;
  const int wr = (w >> 1) * 64;
  const int wc = (w & 1) * 64;
  const int laneM = lane & 15;
  const int q4 = lane >> 4;

#pragma unroll
  for (int i = 0; i < 4; ++i)
#pragma unroll
    for (int j = 0; j < 4; ++j)
      acc[i][j] = f32x4{0.f, 0.f, 0.f, 0.f};

  const int off0 = w * 1024 + lane * 16;           // linear LDS dest (bytes)
  const int off1 = off0 + 4096;
  const int rA0 = off0 >> 6;
  const int rA1 = off1 >> 6;
  const int scb = (((lane & 3) ^ ((lane >> 3) & 3)) << 4);  // swizzled src chunk

  const size_t sA = (size_t)lda * 2;
  const size_t sB = (size_t)ldb * 2;
  const char* pA0 = (const char*)Abase + (size_t)rA0 * sA + scb;
  const char* pA1 = (const char*)Abase + (size_t)rA1 * sA + scb;
  const char* pB0 = (const char*)Bbase + (size_t)rA0 * sB + scb;
  const char* pB1 = (const char*)Bbase + (size_t)rA1 * sB + scb;
  char* dA0 = (char*)&lA[0][0] + off0;
  char* dA1 = (char*)&lA[0][0] + off1;
  char* dB0 = (char*)&lB[0][0] + off0;
  char* dB1 = (char*)&lB[0][0] + off1;

  gl_lds16(pA0, dA0); gl_lds16(pA1, dA1);
  gl_lds16(pB0, dB0); gl_lds16(pB1, dB1);
  pA0 += 64; pA1 += 64; pB0 += 64; pB1 += 64;
  __syncthreads();

  const int rdswz = ((q4 ^ ((laneM >> 1) & 3)) << 4);

  for (int it = 0; it < nIter; ++it) {
    const int cur = it & 1;
    const int nb = cur ^ 1;
    if (it + 1 < nIter) {
      gl_lds16(pA0, dA0 + nb * 8192);
      gl_lds16(pA1, dA1 + nb * 8192);
      gl_lds16(pB0, dB0 + nb * 8192);
      gl_lds16(pB1, dB1 + nb * 8192);
      pA0 += 64; pA1 += 64; pB0 += 64; pB1 += 64;
    }
    const char* aRd = (const char*)&lA[cur][0] + (wr + laneM) * 64 + rdswz;
    const char* bRd = (const char*)&lB[cur][0] + (wc + laneM) * 64 + rdswz;
    bf16x8 af[4], bfr[4];
#pragma unroll
    for (int t = 0; t < 4; ++t) {
      af[t]  = *(const bf16x8*)(aRd + t * 1024);
      bfr[t] = *(const bf16x8*)(bRd + t * 1024);
    }
#pragma unroll
    for (int i = 0; i < 4; ++i)
#pragma unroll
      for (int j = 0; j < 4; ++j)
        acc[i][j] = MFMA16(af[i], bfr[j], acc[i][j]);
    if (it + 1 < nIter) __syncthreads();
  }
}

// ---------- GEMM kernels with fused epilogues ----------
// __launch_bounds__(256,4): 4 blocks/CU resident (LDS 32KB*4=128<=160KB).

// qkv: C = h @ w_attnT^T + b_attn; q,k -> [bh][t][d]; v -> [bh][d][t] (V^T)
__global__ __launch_bounds__(256, 4) void gemm_qkv(
    const u16* __restrict__ A, const u16* __restrict__ Bt,
    const float* __restrict__ bias,
    u16* __restrict__ qo, u16* __restrict__ ko, u16* __restrict__ vo)
{
  f32x4 acc[4][4];
  int m0 = blockIdx.y * 128, n0 = blockIdx.x * 128;
  gemm_mainloop_db(A + (size_t)m0 * 1024, Bt + (size_t)n0 * 1024, 1024, 1024, 32, acc);
  const int lane = threadIdx.x & 63, w = threadIdx.x >> 6;
  const int wr = (w >> 1) * 64, wc = (w & 1) * 64;
  const int laneM = lane & 15, q4 = lane >> 4;
  const int which = (n0 >> 10);
#pragma unroll
  for (int ti = 0; ti < 4; ++ti) {
#pragma unroll
    for (int tj = 0; tj < 4; ++tj) {
      int n = n0 + wc + tj * 16 + laneM;
      int c = n & 1023;
      int hh = c >> 6, d = c & 63;
      float bval = bias[n];
      if (which == 2) {
        int m0r = m0 + wr + ti * 16 + q4 * 4;
        int b = m0r >> 10, t0 = m0r & 1023;
        ushort4 o4;
        o4.x = f2bf(acc[ti][tj][0] + bval);
        o4.y = f2bf(acc[ti][tj][1] + bval);
        o4.z = f2bf(acc[ti][tj][2] + bval);
        o4.w = f2bf(acc[ti][tj][3] + bval);
        *(ushort4*)&vo[((size_t)((b * 16 + hh) * 64 + d)) * 1024 + t0] = o4;
      } else {
        u16* dst = (which == 0) ? qo : ko;
#pragma unroll
        for (int r = 0; r < 4; ++r) {
          int m = m0 + wr + ti * 16 + q4 * 4 + r;
          int b = m >> 10, t = m & 1023;
          dst[((size_t)((b * 16 + hh) * 1024 + t)) * 64 + d] = f2bf(acc[ti][tj][r] + bval);
        }
      }
    }
  }
}

// proj: x2 = (x + y @ w_projT^T + b_proj) * mask[row]
__global__ __launch_bounds__(256, 4) void gemm_proj(
    const u16* __restrict__ A, const u16* __restrict__ Bt,
    const float* __restrict__ bias, const float* __restrict__ xin,
    const float* __restrict__ maskv, float* __restrict__ x2)
{
  f32x4 acc[4][4];
  int m0 = blockIdx.y * 128, n0 = blockIdx.x * 128;
  gemm_mainloop_db(A + (size_t)m0 * 1024, Bt + (size_t)n0 * 1024, 1024, 1024, 32, acc);
  const int lane = threadIdx.x & 63, w = threadIdx.x >> 6;
  const int wr = (w >> 1) * 64, wc = (w & 1) * 64;
  const int laneM = lane & 15, q4 = lane >> 4;
#pragma unroll
  for (int ti = 0; ti < 4; ++ti) {
#pragma unroll
    for (int tj = 0; tj < 4; ++tj) {
      int n = n0 + wc + tj * 16 + laneM;
      float bval = bias[n];
#pragma unroll
      for (int r = 0; r < 4; ++r) {
        int m = m0 + wr + ti * 16 + q4 * 4 + r;
        float v = xin[(size_t)m * 1024 + n] + acc[ti][tj][r] + bval;
        x2[(size_t)m * 1024 + n] = v * maskv[m];
      }
    }
  }
}

// fc: f = gelu(h2 @ w_fcT^T + b_fc) -> bf16   (fast tanh-form GELU)
__global__ __launch_bounds__(256, 4) void gemm_fc(
    const u16* __restrict__ A, const u16* __restrict__ Bt,
    const float* __restrict__ bias, u16* __restrict__ fo)
{
  f32x4 acc[4][4];
  int m0 = blockIdx.y * 128, n0 = blockIdx.x * 128;
  gemm_mainloop_db(A + (size_t)m0 * 1024, Bt + (size_t)n0 * 1024, 1024, 1024, 32, acc);
  const int lane = threadIdx.x & 63, w = threadIdx.x >> 6;
  const int wr = (w >> 1) * 64, wc = (w & 1) * 64;
  const int laneM = lane & 15, q4 = lane >> 4;
#pragma unroll
  for (int ti = 0; ti < 4; ++ti) {
#pragma unroll
    for (int tj = 0; tj < 4; ++tj) {
      int n = n0 + wc + tj * 16 + laneM;
      float bval = bias[n];
#pragma unroll
      for (int r = 0; r < 4; ++r) {
        int m = m0 + wr + ti * 16 + q4 * 4 + r;
        fo[(size_t)m * 4096 + n] = f2bf(gelu_fast(acc[ti][tj][r] + bval));
      }
    }
  }
}

// fc2 split-K=4, XCD-swizzled, bf16 partials.
__global__ __launch_bounds__(256, 4) void gemm_fc2_splitk(
    const u16* __restrict__ A, const u16* __restrict__ Bt,
    u16* __restrict__ pall)
{
  int id = blockIdx.x;            // 0..1023
  int r = id & 7, j = id >> 3;    // r = XCD slot, j = 0..127
  int mt = r * 4 + (j >> 5);      // m-tile 0..31 (4 per XCD)
  int rem = j & 31;
  int n0 = (rem & 7) * 128;       // n fastest: same-XCD neighbors share A slice
  int kz = rem >> 3;              // k-quarter 0..3
  int m0 = mt * 128;
  f32x4 acc[4][4];
  gemm_mainloop_db(A + (size_t)m0 * 4096 + kz * 1024,
                   Bt + (size_t)n0 * 4096 + kz * 1024, 4096, 4096, 32, acc);
  u16* p = pall + (size_t)kz * 4096 * 1024;
  const int lane = threadIdx.x & 63, w = threadIdx.x >> 6;
  const int wr = (w >> 1) * 64, wc = (w & 1) * 64;
  const int laneM = lane & 15, q4 = lane >> 4;
#pragma unroll
  for (int ti = 0; ti < 4; ++ti) {
#pragma unroll
    for (int tj = 0; tj < 4; ++tj) {
      int n = n0 + wc + tj * 16 + laneM;
#pragma unroll
      for (int r2 = 0; r2 < 4; ++r2) {
        int m = m0 + wr + ti * 16 + q4 * 4 + r2;
        p[(size_t)m * 1024 + n] = f2bf(acc[ti][tj][r2]);
      }
    }
  }
}

// out = x2 + b_fc2 + sum_z p[z]   (p bf16)
__global__ __launch_bounds__(256) void fc2_finalize(
    const float* __restrict__ x2, const float* __restrict__ bias,
    const u16* __restrict__ pall, float* __restrict__ out)
{
  int i = blockIdx.x * 256 + threadIdx.x;      // float4 index
  int col4 = i & 255;
  float4 a = ((const float4*)x2)[i];
  float4 b = ((const float4*)bias)[col4];
  float s0 = a.x + b.x, s1 = a.y + b.y, s2 = a.z + b.z, s3 = a.w + b.w;
#pragma unroll
  for (int z = 0; z < 4; ++z) {
    ushort4 u = ((const ushort4*)(pall + (size_t)z * 4194304))[i];
    s0 += bf2f(u.x); s1 += bf2f(u.y); s2 += bf2f(u.z); s3 += bf2f(u.w);
  }
  float4 o; o.x = s0; o.y = s1; o.z = s2; o.w = s3;
  ((float4*)out)[i] = o;
}

// ---------- attention: 8 waves/block, q-tile=128 (16 rows/wave), two-pass,
// double-buffered K/V with register-staged prefetch (one barrier per k-tile),
// LDS importance accumulator, s_setprio around MFMA clusters.  V^T layout.
// r9 grid map (fixes r8's imbalance while keeping its locality win):
//   XCD locality: bh&7 = id&7  -> all blocks of a head on one XCD
//                 (r8-verified: FETCH 57.5 -> 12.4 MB, conflicts 0).
//   balance:      qbi = slot ^ (7*bit8) with slot=id[5:3], bit8=id[8].
//                 Co-resident blocks i and i+256 flip bit8 -> qbi sums to 7,
//                 so every CU hosts heavy+light = 18 k-tile units (r8's same-
//                 qbi pairing gave 32 -> 72.9us makespan regression).
//   bijective:    bh = id[2:0] | (id[8:6]<<3); per bh, slot id[5:3] free.
// K/V/P tiles [rows][64] u16, 16B-chunk XOR swizzle (chunk ^= row&7) on both
// write and read sides (r8-verified: 0 conflicts). ----------

__global__ __launch_bounds__(512) void attn_fwd(
    const u16* __restrict__ qb, const u16* __restrict__ kb, const u16* __restrict__ vtb,
    u16* __restrict__ yb, float* __restrict__ part)
{
  const int id = blockIdx.x;
  const int qbi = ((id >> 3) & 7) ^ (((id >> 8) & 1) ? 7 : 0);
  const int bh = (id & 7) | (((id >> 6) & 7) << 3);   // id%8 = bh%8 -> same XCD
  const int b = bh >> 4, h = bh & 15;

  const int tid = threadIdx.x, lane = tid & 63, w = tid >> 6;   // w in 0..7
  const int q0 = qbi * 128;
  const int laneM = lane & 15, q4 = lane >> 4;
  const int lm7 = laneM & 7;
  const float scale = 0.125f;

  __shared__ __align__(16) u16 lK[2][64 * 64];
  __shared__ __align__(16) u16 lV[2][64 * 64];
  __shared__ __align__(16) u16 lP[8][16 * 64];
  __shared__ float part_s[1024];
  // 16KB + 16KB + 16KB + 4KB = 52KB

  part_s[tid] = 0.f;
  part_s[tid + 512] = 0.f;

  // wave w owns q rows q0 + w*16 .. +15
  bf16x8 qf[2];
  {
    const u16* qrow = qb + ((size_t)(bh * 1024 + q0 + w * 16 + laneM)) * 64 + q4 * 8;
    qf[0] = *(const bf16x8*)qrow;
    qf[1] = *(const bf16x8*)(qrow + 32);
  }

  const int nkt = 2 * qbi + 2;
  const int srow = tid >> 3;                       // 0..63, one uint4/thread/tile
  const int scol = (tid & 7) * 8;                  // global column (u16)
  const int sdst = srow * 64 + (((tid & 7) ^ (srow & 7)) << 3);  // swizzled LDS dst
  const u16* kbase = kb + (size_t)bh * 65536;
  const u16* vbase = vtb + (size_t)bh * 65536;

  // ---- pass 1: denominators (row sums of exp) ----
  float lrow[4] = {0.f, 0.f, 0.f, 0.f};
  {
    uint4 pk = *(const uint4*)(kbase + (size_t)srow * 64 + scol);
    *(uint4*)&lK[0][sdst] = pk;
    __syncthreads();
    for (int kt = 0; kt < nkt; ++kt) {
      const int cur = kt & 1;
      if (kt + 1 < nkt)
        pk = *(const uint4*)(kbase + (size_t)((kt + 1) * 64 + srow) * 64 + scol);
#pragma unroll
      for (int tj = 0; tj < 4; ++tj) {
        const u16* rowp = &lK[cur][(tj * 16 + laneM) * 64];
        const int c0 = (q4 ^ lm7) << 3;
        bf16x8 k0 = *(const bf16x8*)(rowp + c0);
        bf16x8 k1 = *(const bf16x8*)(rowp + (c0 ^ 32));
        f32x4 z = {0.f, 0.f, 0.f, 0.f};
        __builtin_amdgcn_s_setprio(1);
        z = MFMA16(qf[0], k0, z);
        z = MFMA16(qf[1], k1, z);
        __builtin_amdgcn_s_setprio(0);
        int kc = kt * 64 + tj * 16 + laneM;
#pragma unroll
        for (int r = 0; r < 4; ++r) {
          int qg = q0 + w * 16 + q4 * 4 + r;
          lrow[r] += (kc <= qg) ? __expf(z[r] * scale) : 0.f;
        }
      }
      if (kt + 1 < nkt) *(uint4*)&lK[cur ^ 1][sdst] = pk;
      __syncthreads();
    }
  }
  float linv[4];
#pragma unroll
  for (int r = 0; r < 4; ++r) {
    float s = lrow[r];
    s += __shfl_xor(s, 1); s += __shfl_xor(s, 2);
    s += __shfl_xor(s, 4); s += __shfl_xor(s, 8);
    linv[r] = 1.f / s;
  }

  // ---- pass 2: P (normalized), importance column sums, PV ----
  f32x4 o_[4];
#pragma unroll
  for (int dt = 0; dt < 4; ++dt) o_[dt] = f32x4{0.f, 0.f, 0.f, 0.f};

  {
    uint4 pk = *(const uint4*)(kbase + (size_t)srow * 64 + scol);
    uint4 pv = *(const uint4*)(vbase + (size_t)srow * 1024 + scol);
    *(uint4*)&lK[0][sdst] = pk;
    *(uint4*)&lV[0][sdst] = pv;
    __syncthreads();
    for (int kt = 0; kt < nkt; ++kt) {
      const int cur = kt & 1;
      if (kt + 1 < nkt) {
        pk = *(const uint4*)(kbase + (size_t)((kt + 1) * 64 + srow) * 64 + scol);
        pv = *(const uint4*)(vbase + (size_t)srow * 1024 + (kt + 1) * 64 + scol);
      }
      u16* lPw = &lP[w][0];
#pragma unroll
      for (int tj = 0; tj < 4; ++tj) {
        const u16* rowp = &lK[cur][(tj * 16 + laneM) * 64];
        const int c0 = (q4 ^ lm7) << 3;
        bf16x8 k0 = *(const bf16x8*)(rowp + c0);
        bf16x8 k1 = *(const bf16x8*)(rowp + (c0 ^ 32));
        f32x4 z = {0.f, 0.f, 0.f, 0.f};
        __builtin_amdgcn_s_setprio(1);
        z = MFMA16(qf[0], k0, z);
        z = MFMA16(qf[1], k1, z);
        __builtin_amdgcn_s_setprio(0);
        int kc = kt * 64 + tj * 16 + laneM;
        float cs = 0.f;
#pragma unroll
        for (int r = 0; r < 4; ++r) {
          int qg = q0 + w * 16 + q4 * 4 + r;
          float pvf = (kc <= qg) ? __expf(z[r] * scale) * linv[r] : 0.f;
          cs += pvf;
          int prow = q4 * 4 + r;                 // local q row 0..15
          int col = tj * 16 + laneM;             // k col 0..63
          lPw[prow * 64 + ((((col >> 3) ^ (prow & 7)) << 3) | (col & 7))] = f2bf(pvf);
        }
        cs += __shfl_xor(cs, 16);
        cs += __shfl_xor(cs, 32);
        if (lane < 16) atomicAdd(&part_s[kt * 64 + tj * 16 + lane], cs);
      }
      __builtin_amdgcn_s_setprio(1);
#pragma unroll
      for (int ss = 0; ss < 2; ++ss) {
        const int pc = (((ss << 2) | q4) ^ lm7) << 3;
        bf16x8 pf = *(const bf16x8*)&lP[w][laneM * 64 + pc];
#pragma unroll
        for (int dt = 0; dt < 4; ++dt) {
          bf16x8 vf = *(const bf16x8*)&lV[cur][(dt * 16 + laneM) * 64 + pc];
          o_[dt] = MFMA16(pf, vf, o_[dt]);
        }
      }
      __builtin_amdgcn_s_setprio(0);
      if (kt + 1 < nkt) {
        *(uint4*)&lK[cur ^ 1][sdst] = pk;
        *(uint4*)&lV[cur ^ 1][sdst] = pv;
      }
      __syncthreads();
    }
  }

  // flush importance: one global atomicAdd per valid column
  const int kmax = nkt * 64;
  for (int i = tid; i < kmax; i += 512)
    atomicAdd(&part[(size_t)bh * 1024 + i], part_s[i]);

#pragma unroll
  for (int dt = 0; dt < 4; ++dt)
#pragma unroll
    for (int r = 0; r < 4; ++r) {
      int qg = q0 + w * 16 + q4 * 4 + r;
      yb[((size_t)(b * 1024 + qg)) * 1024 + h * 64 + dt * 16 + laneM] = f2bf(o_[dt][r]);
    }
}

// ---------- importance -> mask ----------

__global__ __launch_bounds__(256) void finalize_mask(
    const float* __restrict__ part, const float* __restrict__ amask,
    const float* __restrict__ thr, float* __restrict__ mask_ws,
    float* __restrict__ out_mask, float* __restrict__ out_loss)
{
  int i = blockIdx.x * 256 + threadIdx.x;
  if (i >= 4096) return;
  int b = i >> 10;
  int t = i & 1023;
  float s = 0.f;
#pragma unroll
  for (int hh = 0; hh < 16; ++hh) s += part[(size_t)(b * 16 + hh) * 1024 + t];
  float imp = s * (1.0f / 16384.0f);
  float mv = (imp >= thr[0]) ? amask[i] : 0.f;
  mask_ws[i] = mv;
  out_mask[i] = mv;
  if (i == 0) out_loss[0] = 0.f;
}

// ---------- host ----------

extern "C" void kernel_launch(void* const* d_in, const int* in_sizes, int n_in,
                              void* d_out, int out_size, void* d_ws, size_t ws_size,
                              hipStream_t stream) {
  const float* x      = (const float*)d_in[0];
  const float* amask  = (const float*)d_in[1];
  const float* ln1w   = (const float*)d_in[2];
  const float* ln1b   = (const float*)d_in[3];
  const float* w_attn = (const float*)d_in[4];
  const float* b_attn = (const float*)d_in[5];
  const float* w_proj = (const float*)d_in[6];
  const float* b_proj = (const float*)d_in[7];
  const float* thr    = (const float*)d_in[8];
  const float* ln2w   = (const float*)d_in[9];
  const float* ln2b   = (const float*)d_in[10];
  const float* w_fc   = (const float*)d_in[11];
  const float* b_fc   = (const float*)d_in[12];
  const float* w_fc2  = (const float*)d_in[13];
  const float* b_fc2  = (const float*)d_in[14];
  float* out = (float*)d_out;

  char* ws = (char*)d_ws;
  size_t off = 0;
  auto alloc = [&](size_t bytes) -> char* {
    char* p = ws + off;
    off += (bytes + 255) & ~(size_t)255;
    return p;
  };
  u16* wattnT = (u16*)alloc((size_t)3072 * 1024 * 2);
  u16* wprojT = (u16*)alloc((size_t)1024 * 1024 * 2);
  u16* wfcT   = (u16*)alloc((size_t)4096 * 1024 * 2);
  u16* wfc2T  = (u16*)alloc((size_t)1024 * 4096 * 2);
  u16* hbuf   = (u16*)alloc((size_t)4096 * 1024 * 2);
  // qbuf/kbuf/vtbuf/ybuf: 4 x 8 MB, contiguous; dead before fc2 (aliased as pall)
  u16* qbuf   = (u16*)alloc((size_t)64 * 1024 * 64 * 2);
  u16* kbuf   = (u16*)alloc((size_t)64 * 1024 * 64 * 2);
  u16* vtbuf  = (u16*)alloc((size_t)64 * 64 * 1024 * 2);
  u16* ybuf   = (u16*)alloc((size_t)4096 * 1024 * 2);
  float* part = (float*)alloc((size_t)64 * 1024 * 4);
  float* maskws = (float*)alloc((size_t)4096 * 4);
  float* x2   = (float*)alloc((size_t)4096 * 1024 * 4);
  u16* h2     = (u16*)alloc((size_t)4096 * 1024 * 2);
  u16* fbuf   = (u16*)alloc((size_t)4096 * 4096 * 2);

  u16* pall = qbuf;   // 4 bf16 partials x 8 MB alias q/k/vt/y

  transpose_all<<<3072, 256, 0, stream>>>(
      w_attn, w_proj, w_fc, w_fc2, wattnT, wprojT, wfcT, wfc2T);

  hipMemsetAsync(part, 0, (size_t)64 * 1024 * 4, stream);

  ln_bf16<<<4096, 256, 0, stream>>>(x, ln1w, ln1b, hbuf);

  gemm_qkv<<<dim3(24, 32), 256, 0, stream>>>(hbuf, wattnT, b_attn, qbuf, kbuf, vtbuf);

  attn_fwd<<<512, 512, 0, stream>>>(qbuf, kbuf, vtbuf, ybuf, part);

  finalize_mask<<<16, 256, 0, stream>>>(part, amask, thr, maskws,
                                        out + 4194304, out + 4198400);

  gemm_proj<<<dim3(8, 32), 256, 0, stream>>>(ybuf, wprojT, b_proj, x, maskws, x2);

  ln_bf16<<<4096, 256, 0, stream>>>(x2, ln2w, ln2b, h2);

  gemm_fc<<<dim3(32, 32), 256, 0, stream>>>(h2, wfcT, b_fc, fbuf);

  gemm_fc2_splitk<<<1024, 256, 0, stream>>>(fbuf, wfc2T, pall);

  fc2_finalize<<<4096, 256, 0, stream>>>(x2, b_fc2, pall, out);
}